// Round 7
// baseline (3045.175 us; speedup 1.0000x reference)
//
#include <hip/hip_runtime.h>

typedef _Float16 h16x8 __attribute__((ext_vector_type(8)));
typedef _Float16 h16x4 __attribute__((ext_vector_type(4)));
typedef float fx4 __attribute__((ext_vector_type(4)));
typedef unsigned int u32x4 __attribute__((ext_vector_type(4)));
typedef unsigned long long ull;

// V=32001 E=512 H=512 LE=512 B=128 T=512, 5H=2560
#define PRE_S 2560.0f
#define PRE_INV (1.0f / 2560.0f)

// ---------------- fp32 -> fp16 bulk convert (i2h weights) ----------------
__global__ __launch_bounds__(256) void f2h_kernel(const float* __restrict__ src,
                                                  _Float16* __restrict__ dst,
                                                  int n4) {
  int i = blockIdx.x * 256 + threadIdx.x;
  if (i < n4) {
    float4 v = ((const float4*)src)[i];
    h16x4 o = {(_Float16)v.x, (_Float16)v.y, (_Float16)v.z, (_Float16)v.w};
    *(h16x4*)&dst[i * 4] = o;
  }
}

// ---------------- pre = gather(embed) @ i2h_w^T, int8 out (x2560 scale)
// pre8 layout wg-local: pre8[t][j][b][g][u]  (j=0..63, b=0..127, g=0..4, u=0..7)
__global__ __launch_bounds__(256) void gemm1_kernel(
    const int* __restrict__ label, const int* __restrict__ label_len,
    const float* __restrict__ embed_w,        // fp32 [32001][512]
    const _Float16* __restrict__ Bh,          // i2h fp16 [2560][512]
    signed char* __restrict__ pre8) {
  const int bx = blockIdx.x;          // N tile 0..19
  const int by = blockIdx.y;          // M tile 0..511
  const int bidx = by >> 2;           // batch
  const int t0 = (by & 3) * 128;      // t range start
  if (t0 > label_len[bidx]) return;   // this tile's pre is never read

  const int tid = threadIdx.x;
  const int lane = tid & 63;
  const int wv = tid >> 6;
  const int wm = (wv & 1) * 64;
  const int wn = (wv >> 1) * 64;

  __shared__ _Float16 As[128 * 40];
  __shared__ _Float16 Bs[128 * 40];

  fx4 zero = {0.f, 0.f, 0.f, 0.f};
  fx4 acc[4][4];
  for (int a = 0; a < 4; a++)
    for (int b = 0; b < 4; b++) acc[a][b] = zero;

#pragma unroll 1
  for (int k0 = 0; k0 < 512; k0 += 32) {
#pragma unroll
    for (int q = 0; q < 2; q++) {
      int chunk = tid + q * 256;
      int row = chunk >> 2;
      int ko = (chunk & 3) * 8;
      int arow = label[bidx * 512 + t0 + row];
      const float* ap = &embed_w[(size_t)arow * 512 + k0 + ko];
      float4 a0 = *(const float4*)ap;
      float4 a1 = *(const float4*)(ap + 4);
      h16x8 av = {(_Float16)a0.x, (_Float16)a0.y, (_Float16)a0.z, (_Float16)a0.w,
                  (_Float16)a1.x, (_Float16)a1.y, (_Float16)a1.z, (_Float16)a1.w};
      h16x8 bv = *(const h16x8*)&Bh[(size_t)(bx * 128 + row) * 512 + k0 + ko];
      *(h16x8*)&As[row * 40 + ko] = av;
      *(h16x8*)&Bs[row * 40 + ko] = bv;
    }
    __syncthreads();
    h16x8 af[4], bfr[4];
#pragma unroll
    for (int i = 0; i < 4; i++) {
      af[i]  = *(const h16x8*)&As[(wm + i * 16 + (lane & 15)) * 40 + (lane >> 4) * 8];
      bfr[i] = *(const h16x8*)&Bs[(wn + i * 16 + (lane & 15)) * 40 + (lane >> 4) * 8];
    }
#pragma unroll
    for (int mi = 0; mi < 4; mi++)
#pragma unroll
      for (int ni = 0; ni < 4; ni++)
        acc[mi][ni] = __builtin_amdgcn_mfma_f32_16x16x32_f16(af[mi], bfr[ni], acc[mi][ni], 0, 0, 0);
    __syncthreads();
  }

#pragma unroll
  for (int mi = 0; mi < 4; mi++)
#pragma unroll
    for (int ni = 0; ni < 4; ni++)
#pragma unroll
      for (int r = 0; r < 4; r++) {
        int rowm = wm + mi * 16 + (lane >> 4) * 4 + r;
        int t = t0 + rowm;
        int n = bx * 128 + wn + ni * 16 + (lane & 15);
        float v = acc[mi][ni][r] * PRE_S;
        int q = (int)rintf(v);
        q = q > 127 ? 127 : (q < -127 ? -127 : q);
        int g = n >> 9, ju = n & 511, j = ju >> 3, u = ju & 7;
        pre8[(((size_t)t * 64 + j) * 128 + bidx) * 40 + g * 8 + u] = (signed char)q;
      }
}

// ---------------- persistent LSTM scan: 128 wgs = 2 independent 64-wg groups.
// wg (j = blk>>1, bh = blk&1) owns units [8j,8j+8) x batches [64bh, 64bh+64).
// Cross-wg traffic (hbuf, flags) via LLC-direct accesses (sc0 sc1), no fences.
// h_{t-1} loaded straight into MFMA A-operand registers with 16 coherent
// global_load_dwordx4 (16B/lane), single vmcnt(0) -- no LDS staging.
#define NWG 128
__global__ __launch_bounds__(256, 1) void lstm_kernel(
    const int* __restrict__ label_len,
    const float* __restrict__ h2h_w,   // [2560][512] fp32
    const float* __restrict__ h2h_b,   // [2560]
    const float* __restrict__ i2h_b,   // [2560]
    const signed char* __restrict__ pre8,    // [512][64][128][40] int8
    _Float16* __restrict__ hbuf,             // [2][128][512] fp16
    float* __restrict__ xsel,                // [128][512] fp32
    int* __restrict__ flags) {               // 128 flags, 128B apart
  const int j   = blockIdx.x >> 1;
  const int bh  = blockIdx.x & 1;
  const int tid = threadIdx.x;
  const int lane = tid & 63;
  const int wv = tid >> 6;

  __shared__ _Float16 Wl[3 * 16 * 64 * 8];   // 48 KB, MFMA B-operand order
  __shared__ _Float16 s_s[64 * 48];          // 6 KB
  __shared__ int ll_s[64];

  for (int slot = tid; slot < 3 * 16 * 64; slot += 256) {
    int nt = slot / (16 * 64);
    int rem = slot - nt * (16 * 64);
    int kt = rem >> 6;
    int l = rem & 63;
    int p = nt * 16 + (l & 15);            // packed col: g*8+u (p<40), else zero pad
    int k0 = kt * 32 + (l >> 4) * 8;
    h16x8 tv;
    if (p < 40) {
      int r = (p >> 3) * 512 + j * 8 + (p & 7);
      const float* src = h2h_w + (size_t)r * 512 + k0;
#pragma unroll
      for (int q = 0; q < 8; q++) tv[q] = (_Float16)src[q];
    } else {
#pragma unroll
      for (int q = 0; q < 8; q++) tv[q] = (_Float16)0.f;
    }
    *(h16x8*)&Wl[slot * 8] = tv;
  }
  if (tid < 64) ll_s[tid] = label_len[bh * 64 + tid];

  // gate ownership: thread -> batch b'=tid>>2, units (ue, ue+1)
  const int ue = (tid & 3) * 2;
  const int bp = tid >> 2;             // 0..63
  float bias_r[2][5];
#pragma unroll
  for (int uu = 0; uu < 2; uu++)
#pragma unroll
    for (int g = 0; g < 5; g++)
      bias_r[uu][g] = h2h_b[g * 512 + j * 8 + ue + uu] + i2h_b[g * 512 + j * 8 + ue + uu];

  float c_reg[2] = {0.f, 0.f};
  __syncthreads();

#pragma unroll 1
  for (int t = 0; t < 512; ++t) {
    // prefetch this wg's private pre[t] block (plain cached; overlaps poll)
    unsigned short pr[5];
    {
      const signed char* pt = pre8 + (((size_t)t * 64 + j) * 128 + bh * 64) * 40;
#pragma unroll
      for (int g = 0; g < 5; g++)
        pr[g] = *(const unsigned short*)&pt[bp * 40 + g * 8 + ue];
    }

    if (t > 0) {
      // wait for all 64 same-bh producers (lane-parallel distributed flags)
      if (wv == 0) {
        const int* fp = flags + (bh * 64 + lane) * 32;
        while (true) {
          int v = __hip_atomic_load(fp, __ATOMIC_RELAXED, __HIP_MEMORY_SCOPE_AGENT);
          if (__ballot(v >= t) == 0xFFFFFFFFFFFFFFFFull) break;
          __builtin_amdgcn_s_sleep(1);
        }
      }
      __syncthreads();

      // load 16 A-fragments (this wave's 16 batch rows) straight from LLC
      const _Float16* hp = hbuf + ((t - 1) & 1) * (128 * 512)
                         + (bh * 64 + wv * 16 + (lane & 15)) * 512 + (lane >> 4) * 8;
      u32x4 areg[16];
#pragma unroll
      for (int kt = 0; kt < 16; ++kt) {
        const void* ap = (const void*)(hp + kt * 32);
        asm volatile("global_load_dwordx4 %0, %1, off sc0 sc1"
                     : "=v"(areg[kt]) : "v"(ap) : "memory");
      }
      asm volatile("s_waitcnt vmcnt(0)" ::: "memory");

      // GEMM: wave wv owns m-tile wv (16 rows); 3 n-tiles; K=512
      fx4 zero = {0.f, 0.f, 0.f, 0.f};
      fx4 acc[3] = {zero, zero, zero};
#pragma unroll
      for (int kt = 0; kt < 16; ++kt) {
        union { u32x4 u; h16x8 v; } a;
        a.u = areg[kt];
#pragma unroll
        for (int nt = 0; nt < 3; nt++) {
          h16x8 bfr = *(const h16x8*)&Wl[((nt * 16 + kt) * 64 + lane) * 8];
          acc[nt] = __builtin_amdgcn_mfma_f32_16x16x32_f16(a.v, bfr, acc[nt], 0, 0, 0);
        }
      }
#pragma unroll
      for (int nt = 0; nt < 3; nt++)
#pragma unroll
        for (int r = 0; r < 4; r++) {
          int b = wv * 16 + (lane >> 4) * 4 + r;
          s_s[b * 48 + nt * 16 + (lane & 15)] = (_Float16)acc[nt][r];
        }
      __syncthreads();
    }

    // gate phase
    _Float16* hn = hbuf + (t & 1) * (128 * 512);
    float nh2[2];
#pragma unroll
    for (int uu = 0; uu < 2; uu++) {
      float sv[5];
#pragma unroll
      for (int g = 0; g < 5; g++) {
        signed char qb = (signed char)(uu == 0 ? (pr[g] & 0xFF) : (pr[g] >> 8));
        float base = (t > 0) ? (float)s_s[bp * 48 + g * 8 + ue + uu] : 0.f;
        sv[g] = base + (float)qb * PRE_INV + bias_r[uu][g];
      }
      float ing = 1.f / (1.f + __expf(-sv[0]));
      float fg  = 1.f / (1.f + __expf(-sv[1]));
      float og  = 1.f / (1.f + __expf(-sv[2]));
      float itv = fmaxf(sv[3], sv[4]);
      float nc = fg * c_reg[uu] + ing * itv;
      c_reg[uu] = nc;
      nh2[uu] = og * tanhf(nc);
    }
    {
      union { _Float16 h[2]; unsigned int u; } pk;
      pk.h[0] = (_Float16)nh2[0];
      pk.h[1] = (_Float16)nh2[1];
      __hip_atomic_store((unsigned int*)&hn[(bh * 64 + bp) * 512 + j * 8 + ue], pk.u,
                         __ATOMIC_RELAXED, __HIP_MEMORY_SCOPE_AGENT);
      if (ll_s[bp] == t) {
        union { float f[2]; ull u; } xk;
        xk.f[0] = nh2[0];
        xk.f[1] = nh2[1];
        __hip_atomic_store((ull*)&xsel[(bh * 64 + bp) * 512 + j * 8 + ue], xk.u,
                           __ATOMIC_RELAXED, __HIP_MEMORY_SCOPE_AGENT);
      }
    }

    // drain h stores to LLC, then arrive on our own flag line
    asm volatile("s_waitcnt vmcnt(0)" ::: "memory");
    __syncthreads();
    if (tid == 0)
      __hip_atomic_store(flags + (bh * 64 + j) * 32, t + 1,
                         __ATOMIC_RELAXED, __HIP_MEMORY_SCOPE_AGENT);
  }
}

// ---------------- small fp32 GEMM: Y[128,512] = X[128,512] @ W[512,512]^T + bias
__global__ __launch_bounds__(256) void fgemm_kernel(
    const float* __restrict__ X, const float* __restrict__ W,
    const float* __restrict__ bias, float* __restrict__ Y) {
  const int n0 = blockIdx.x * 64;
  const int m0 = blockIdx.y * 64;
  const int tid = threadIdx.x;
  const int tx = tid & 15, ty = tid >> 4;

  __shared__ float Xs[64 * 68];
  __shared__ float Wt[64 * 68];

  float acc[4][4] = {};
#pragma unroll 1
  for (int k0 = 0; k0 < 512; k0 += 64) {
#pragma unroll
    for (int q = 0; q < 4; q++) {
      int id = tid + q * 256;
      int r = id >> 4, c = id & 15;
      float4 xv = *(const float4*)&X[(m0 + r) * 512 + k0 + c * 4];
      *(float4*)&Xs[r * 68 + c * 4] = xv;
      float4 wvv = *(const float4*)&W[(n0 + r) * 512 + k0 + c * 4];
      Wt[(c * 4 + 0) * 68 + r] = wvv.x;
      Wt[(c * 4 + 1) * 68 + r] = wvv.y;
      Wt[(c * 4 + 2) * 68 + r] = wvv.z;
      Wt[(c * 4 + 3) * 68 + r] = wvv.w;
    }
    __syncthreads();
#pragma unroll 4
    for (int kk = 0; kk < 64; kk++) {
      float a[4], b[4];
#pragma unroll
      for (int i = 0; i < 4; i++) a[i] = Xs[(ty * 4 + i) * 68 + kk];
#pragma unroll
      for (int jj = 0; jj < 4; jj++) b[jj] = Wt[kk * 68 + tx * 4 + jj];
#pragma unroll
      for (int i = 0; i < 4; i++)
#pragma unroll
        for (int jj = 0; jj < 4; jj++) acc[i][jj] += a[i] * b[jj];
    }
    __syncthreads();
  }
#pragma unroll
  for (int i = 0; i < 4; i++)
#pragma unroll
    for (int jj = 0; jj < 4; jj++) {
      int n = n0 + tx * 4 + jj;
      Y[(m0 + ty * 4 + i) * 512 + n] = acc[i][jj] + bias[n];
    }
}

// ---------------- batchnorm over batch dim (in-place), optional relu
__global__ __launch_bounds__(256) void bn_kernel(float* __restrict__ Y,
    const float* __restrict__ gam, const float* __restrict__ bet, int relu) {
  const int cx = threadIdx.x & 15;
  const int rg = threadIdx.x >> 4;
  const int col = blockIdx.x * 16 + cx;
  __shared__ float rs[16 * 17], rs2[16 * 17];
  float s = 0.f, s2 = 0.f;
#pragma unroll
  for (int i = 0; i < 8; i++) {
    float v = Y[(rg * 8 + i) * 512 + col];
    s += v; s2 += v * v;
  }
  rs[rg * 17 + cx] = s;
  rs2[rg * 17 + cx] = s2;
  __syncthreads();
  if (threadIdx.x < 16) {
    float S = 0.f, S2 = 0.f;
#pragma unroll
    for (int q = 0; q < 16; q++) { S += rs[q * 17 + threadIdx.x]; S2 += rs2[q * 17 + threadIdx.x]; }
    float mean = S / 128.f;
    float var = S2 / 128.f - mean * mean;
    rs[threadIdx.x] = mean;
    rs2[threadIdx.x] = rsqrtf(var + 1e-5f);
  }
  __syncthreads();
  float mean = rs[cx], rstd = rs2[cx];
  float gv = gam[col], bv = bet[col];
#pragma unroll
  for (int i = 0; i < 8; i++) {
    int idx = (rg * 8 + i) * 512 + col;
    float v = (Y[idx] - mean) * rstd * gv + bv;
    if (relu) v = fmaxf(v, 0.f);
    Y[idx] = v;
  }
}

extern "C" void kernel_launch(void* const* d_in, const int* in_sizes, int n_in,
                              void* d_out, int out_size, void* d_ws, size_t ws_size,
                              hipStream_t stream) {
  const int* label      = (const int*)d_in[0];
  const int* label_len  = (const int*)d_in[1];
  const float* embed_w  = (const float*)d_in[2];
  const float* i2h_w    = (const float*)d_in[3];
  const float* i2h_b    = (const float*)d_in[4];
  const float* h2h_w    = (const float*)d_in[5];
  const float* h2h_b    = (const float*)d_in[6];
  const float* lin0_w   = (const float*)d_in[7];
  const float* lin0_b   = (const float*)d_in[8];
  const float* bn0_g    = (const float*)d_in[9];
  const float* bn0_b    = (const float*)d_in[10];
  const float* lin1_w   = (const float*)d_in[11];
  const float* lin1_b   = (const float*)d_in[12];
  const float* bn1_g    = (const float*)d_in[13];
  const float* bn1_b    = (const float*)d_in[14];
  float* out = (float*)d_out;
  char* ws = (char*)d_ws;

  const size_t OFF_FLAGS = 0;                                      // 16 KB
  const size_t OFF_I2H  = 16384;
  const size_t OFF_PRE  = OFF_I2H + (size_t)2560 * 512 * 2;        // fp16 i2h
  const size_t OFF_H    = OFF_PRE + (size_t)512 * 128 * 2560;      // int8 pre
  const size_t OFF_XSEL = OFF_H + (size_t)2 * 128 * 512 * 2;       // fp16 hbuf
  const size_t OFF_Y0   = OFF_XSEL + (size_t)128 * 512 * 4;

  int* flags = (int*)(ws + OFF_FLAGS);
  _Float16* i2h_h = (_Float16*)(ws + OFF_I2H);
  signed char* pre8 = (signed char*)(ws + OFF_PRE);
  _Float16* hbuf = (_Float16*)(ws + OFF_H);
  float* xsel = (float*)(ws + OFF_XSEL);
  float* y0   = (float*)(ws + OFF_Y0);

  hipMemsetAsync(ws + OFF_FLAGS, 0, 16384, stream);

  {
    int n4 = (2560 * 512) / 4;
    f2h_kernel<<<(n4 + 255) / 256, 256, 0, stream>>>(i2h_w, i2h_h, n4);
  }
  gemm1_kernel<<<dim3(20, 512), 256, 0, stream>>>(label, label_len, embed_w, i2h_h, pre8);
  lstm_kernel<<<dim3(NWG), 256, 0, stream>>>(label_len, h2h_w, h2h_b, i2h_b, pre8, hbuf, xsel, flags);
  fgemm_kernel<<<dim3(8, 2), 256, 0, stream>>>(xsel, lin0_w, lin0_b, y0);
  bn_kernel<<<dim3(32), 256, 0, stream>>>(y0, bn0_g, bn0_b, 1);
  fgemm_kernel<<<dim3(8, 2), 256, 0, stream>>>(y0, lin1_w, lin1_b, out);
  bn_kernel<<<dim3(32), 256, 0, stream>>>(out, bn1_g, bn1_b, 0);
}

// Round 8
// 2490.885 us; speedup vs baseline: 1.2225x; 1.2225x over previous
//
#include <hip/hip_runtime.h>

typedef _Float16 h16x8 __attribute__((ext_vector_type(8)));
typedef _Float16 h16x4 __attribute__((ext_vector_type(4)));
typedef float fx4 __attribute__((ext_vector_type(4)));
typedef unsigned int u32x4 __attribute__((ext_vector_type(4)));
typedef unsigned long long ull;

// V=32001 E=512 H=512 LE=512 B=128 T=512, 5H=2560
#define PRE_S 2560.0f
#define PRE_INV (1.0f / 2560.0f)

// ---------------- fp32 -> fp16 bulk convert (i2h weights) ----------------
__global__ __launch_bounds__(256) void f2h_kernel(const float* __restrict__ src,
                                                  _Float16* __restrict__ dst,
                                                  int n4) {
  int i = blockIdx.x * 256 + threadIdx.x;
  if (i < n4) {
    float4 v = ((const float4*)src)[i];
    h16x4 o = {(_Float16)v.x, (_Float16)v.y, (_Float16)v.z, (_Float16)v.w};
    *(h16x4*)&dst[i * 4] = o;
  }
}

// ---------------- pre = gather(embed) @ i2h_w^T, int8 out (x2560 scale)
// pre8 layout wg-local: pre8[t][j][b][g][u]  (j=0..63, b=0..127, g=0..4, u=0..7)
__global__ __launch_bounds__(256) void gemm1_kernel(
    const int* __restrict__ label, const int* __restrict__ label_len,
    const float* __restrict__ embed_w,        // fp32 [32001][512]
    const _Float16* __restrict__ Bh,          // i2h fp16 [2560][512]
    signed char* __restrict__ pre8) {
  const int bx = blockIdx.x;          // N tile 0..19
  const int by = blockIdx.y;          // M tile 0..511
  const int bidx = by >> 2;           // batch
  const int t0 = (by & 3) * 128;      // t range start
  if (t0 > label_len[bidx]) return;   // this tile's pre is never read

  const int tid = threadIdx.x;
  const int lane = tid & 63;
  const int wv = tid >> 6;
  const int wm = (wv & 1) * 64;
  const int wn = (wv >> 1) * 64;

  __shared__ _Float16 As[128 * 40];
  __shared__ _Float16 Bs[128 * 40];

  fx4 zero = {0.f, 0.f, 0.f, 0.f};
  fx4 acc[4][4];
  for (int a = 0; a < 4; a++)
    for (int b = 0; b < 4; b++) acc[a][b] = zero;

#pragma unroll 1
  for (int k0 = 0; k0 < 512; k0 += 32) {
#pragma unroll
    for (int q = 0; q < 2; q++) {
      int chunk = tid + q * 256;
      int row = chunk >> 2;
      int ko = (chunk & 3) * 8;
      int arow = label[bidx * 512 + t0 + row];
      const float* ap = &embed_w[(size_t)arow * 512 + k0 + ko];
      float4 a0 = *(const float4*)ap;
      float4 a1 = *(const float4*)(ap + 4);
      h16x8 av = {(_Float16)a0.x, (_Float16)a0.y, (_Float16)a0.z, (_Float16)a0.w,
                  (_Float16)a1.x, (_Float16)a1.y, (_Float16)a1.z, (_Float16)a1.w};
      h16x8 bv = *(const h16x8*)&Bh[(size_t)(bx * 128 + row) * 512 + k0 + ko];
      *(h16x8*)&As[row * 40 + ko] = av;
      *(h16x8*)&Bs[row * 40 + ko] = bv;
    }
    __syncthreads();
    h16x8 af[4], bfr[4];
#pragma unroll
    for (int i = 0; i < 4; i++) {
      af[i]  = *(const h16x8*)&As[(wm + i * 16 + (lane & 15)) * 40 + (lane >> 4) * 8];
      bfr[i] = *(const h16x8*)&Bs[(wn + i * 16 + (lane & 15)) * 40 + (lane >> 4) * 8];
    }
#pragma unroll
    for (int mi = 0; mi < 4; mi++)
#pragma unroll
      for (int ni = 0; ni < 4; ni++)
        acc[mi][ni] = __builtin_amdgcn_mfma_f32_16x16x32_f16(af[mi], bfr[ni], acc[mi][ni], 0, 0, 0);
    __syncthreads();
  }

#pragma unroll
  for (int mi = 0; mi < 4; mi++)
#pragma unroll
    for (int ni = 0; ni < 4; ni++)
#pragma unroll
      for (int r = 0; r < 4; r++) {
        int rowm = wm + mi * 16 + (lane >> 4) * 4 + r;
        int t = t0 + rowm;
        int n = bx * 128 + wn + ni * 16 + (lane & 15);
        float v = acc[mi][ni][r] * PRE_S;
        int q = (int)rintf(v);
        q = q > 127 ? 127 : (q < -127 ? -127 : q);
        int g = n >> 9, ju = n & 511, j = ju >> 3, u = ju & 7;
        pre8[(((size_t)t * 64 + j) * 128 + bidx) * 40 + g * 8 + u] = (signed char)q;
      }
}

// ---------------- persistent LSTM scan: 128 wgs = 2 independent 64-wg groups.
// wg (j = blk>>1, bh = blk&1) owns units [8j,8j+8) x batches [64bh, 64bh+64).
// h exchanged via hfrag in MFMA-FRAGMENT-MAJOR layout:
//   hfrag[parity][bb=(bh*4+wv)*16+kt][lane][8 halves]
// consumer fragment (wv,kt) = ONE contiguous 1KB block (full line utilization);
// producer (j,bh) writes 4x256B contiguous chunks. All cross-wg traffic via
// LLC-direct (sc0 sc1) accesses, no fences. Distributed per-wg flags.
#define NWG 128
__global__ __launch_bounds__(256, 1) void lstm_kernel(
    const int* __restrict__ label_len,
    const float* __restrict__ h2h_w,   // [2560][512] fp32
    const float* __restrict__ h2h_b,   // [2560]
    const float* __restrict__ i2h_b,   // [2560]
    const signed char* __restrict__ pre8,    // [512][64][128][40] int8
    _Float16* __restrict__ hfrag,            // [2][8*16][64][8] fp16 (256 KB)
    float* __restrict__ xsel,                // [128][512] fp32
    int* __restrict__ flags) {               // 128 flags, 128B apart
  const int j   = blockIdx.x >> 1;
  const int bh  = blockIdx.x & 1;
  const int tid = threadIdx.x;
  const int lane = tid & 63;
  const int wv = tid >> 6;

  __shared__ _Float16 Wl[3 * 16 * 64 * 8];   // 48 KB, MFMA B-operand order
  __shared__ _Float16 s_s[64 * 48];          // 6 KB
  __shared__ int ll_s[64];

  for (int slot = tid; slot < 3 * 16 * 64; slot += 256) {
    int nt = slot / (16 * 64);
    int rem = slot - nt * (16 * 64);
    int kt = rem >> 6;
    int l = rem & 63;
    int p = nt * 16 + (l & 15);            // packed col: g*8+u (p<40), else zero pad
    int k0 = kt * 32 + (l >> 4) * 8;
    h16x8 tv;
    if (p < 40) {
      int r = (p >> 3) * 512 + j * 8 + (p & 7);
      const float* src = h2h_w + (size_t)r * 512 + k0;
#pragma unroll
      for (int q = 0; q < 8; q++) tv[q] = (_Float16)src[q];
    } else {
#pragma unroll
      for (int q = 0; q < 8; q++) tv[q] = (_Float16)0.f;
    }
    *(h16x8*)&Wl[slot * 8] = tv;
  }
  if (tid < 64) ll_s[tid] = label_len[bh * 64 + tid];

  // gate ownership: thread -> batch b'=tid>>2 (bp), units (ue, ue+1)
  const int ue = (tid & 3) * 2;
  const int bp = tid >> 2;             // 0..63
  float bias_r[2][5];
#pragma unroll
  for (int uu = 0; uu < 2; uu++)
#pragma unroll
    for (int g = 0; g < 5; g++)
      bias_r[uu][g] = h2h_b[g * 512 + j * 8 + ue + uu] + i2h_b[g * 512 + j * 8 + ue + uu];

  // producer store slot (fragment-major): block bb, lane_c, sub=ue
  const int pbb = (bh * 4 + (bp >> 4)) * 16 + (j >> 2);
  const int plc = (bp & 15) | ((j & 3) << 4);
  unsigned int* pdst0 = (unsigned int*)(hfrag + (size_t)pbb * 512 + plc * 8 + ue);
  unsigned int* pdst1 = (unsigned int*)(hfrag + 65536 + (size_t)pbb * 512 + plc * 8 + ue);

  float c_reg[2] = {0.f, 0.f};
  __syncthreads();

#pragma unroll 1
  for (int t = 0; t < 512; ++t) {
    // prefetch this wg's private pre[t] block (plain cached; overlaps poll)
    unsigned short pr[5];
    {
      const signed char* pt = pre8 + (((size_t)t * 64 + j) * 128 + bh * 64) * 40;
#pragma unroll
      for (int g = 0; g < 5; g++)
        pr[g] = *(const unsigned short*)&pt[bp * 40 + g * 8 + ue];
    }

    if (t > 0) {
      // wait for all 64 same-bh producers (lane-parallel distributed flags)
      if (wv == 0) {
        const int* fp = flags + (bh * 64 + lane) * 32;
        while (true) {
          int v = __hip_atomic_load(fp, __ATOMIC_RELAXED, __HIP_MEMORY_SCOPE_AGENT);
          if (__ballot(v >= t) == 0xFFFFFFFFFFFFFFFFull) break;
          __builtin_amdgcn_s_sleep(1);
        }
      }
      __syncthreads();

      // load 16 A-fragments: each is a contiguous 1KB block, lane*16B -- fully
      // coalesced LLC reads, issued back-to-back, single vmcnt(0)
      const _Float16* hpb = hfrag + ((t - 1) & 1) * 65536
                          + (size_t)((bh * 4 + wv) * 16) * 512 + lane * 8;
      u32x4 areg[16];
#pragma unroll
      for (int kt = 0; kt < 16; ++kt) {
        const void* ap = (const void*)(hpb + kt * 512);
        asm volatile("global_load_dwordx4 %0, %1, off sc0 sc1"
                     : "=v"(areg[kt]) : "v"(ap) : "memory");
      }
      asm volatile("s_waitcnt vmcnt(0)" ::: "memory");

      // GEMM: wave wv owns m-tile wv (16 rows); 3 n-tiles; K=512
      fx4 zero = {0.f, 0.f, 0.f, 0.f};
      fx4 acc[3] = {zero, zero, zero};
#pragma unroll
      for (int kt = 0; kt < 16; ++kt) {
        union { u32x4 u; h16x8 v; } a;
        a.u = areg[kt];
#pragma unroll
        for (int nt = 0; nt < 3; nt++) {
          h16x8 bfr = *(const h16x8*)&Wl[((nt * 16 + kt) * 64 + lane) * 8];
          acc[nt] = __builtin_amdgcn_mfma_f32_16x16x32_f16(a.v, bfr, acc[nt], 0, 0, 0);
        }
      }
#pragma unroll
      for (int nt = 0; nt < 3; nt++)
#pragma unroll
        for (int r = 0; r < 4; r++) {
          int b = wv * 16 + (lane >> 4) * 4 + r;
          s_s[b * 48 + nt * 16 + (lane & 15)] = (_Float16)acc[nt][r];
        }
      __syncthreads();
    }

    // gate phase
    float nh2[2];
#pragma unroll
    for (int uu = 0; uu < 2; uu++) {
      float sv[5];
#pragma unroll
      for (int g = 0; g < 5; g++) {
        signed char qb = (signed char)(uu == 0 ? (pr[g] & 0xFF) : (pr[g] >> 8));
        float base = (t > 0) ? (float)s_s[bp * 48 + g * 8 + ue + uu] : 0.f;
        sv[g] = base + (float)qb * PRE_INV + bias_r[uu][g];
      }
      float ing = 1.f / (1.f + __expf(-sv[0]));
      float fg  = 1.f / (1.f + __expf(-sv[1]));
      float og  = 1.f / (1.f + __expf(-sv[2]));
      float itv = fmaxf(sv[3], sv[4]);
      float nc = fg * c_reg[uu] + ing * itv;
      c_reg[uu] = nc;
      nh2[uu] = og * tanhf(nc);
    }
    {
      union { _Float16 h[2]; unsigned int u; } pk;
      pk.h[0] = (_Float16)nh2[0];
      pk.h[1] = (_Float16)nh2[1];
      __hip_atomic_store((t & 1) ? pdst1 : pdst0, pk.u,
                         __ATOMIC_RELAXED, __HIP_MEMORY_SCOPE_AGENT);
      if (ll_s[bp] == t) {
        union { float f[2]; ull u; } xk;
        xk.f[0] = nh2[0];
        xk.f[1] = nh2[1];
        __hip_atomic_store((ull*)&xsel[(bh * 64 + bp) * 512 + j * 8 + ue], xk.u,
                           __ATOMIC_RELAXED, __HIP_MEMORY_SCOPE_AGENT);
      }
    }

    // drain h stores to LLC, then arrive on our own flag line
    asm volatile("s_waitcnt vmcnt(0)" ::: "memory");
    __syncthreads();
    if (tid == 0)
      __hip_atomic_store(flags + (bh * 64 + j) * 32, t + 1,
                         __ATOMIC_RELAXED, __HIP_MEMORY_SCOPE_AGENT);
  }
}

// ---------------- small fp32 GEMM: Y[128,512] = X[128,512] @ W[512,512]^T + bias
__global__ __launch_bounds__(256) void fgemm_kernel(
    const float* __restrict__ X, const float* __restrict__ W,
    const float* __restrict__ bias, float* __restrict__ Y) {
  const int n0 = blockIdx.x * 64;
  const int m0 = blockIdx.y * 64;
  const int tid = threadIdx.x;
  const int tx = tid & 15, ty = tid >> 4;

  __shared__ float Xs[64 * 68];
  __shared__ float Wt[64 * 68];

  float acc[4][4] = {};
#pragma unroll 1
  for (int k0 = 0; k0 < 512; k0 += 64) {
#pragma unroll
    for (int q = 0; q < 4; q++) {
      int id = tid + q * 256;
      int r = id >> 4, c = id & 15;
      float4 xv = *(const float4*)&X[(m0 + r) * 512 + k0 + c * 4];
      *(float4*)&Xs[r * 68 + c * 4] = xv;
      float4 wvv = *(const float4*)&W[(n0 + r) * 512 + k0 + c * 4];
      Wt[(c * 4 + 0) * 68 + r] = wvv.x;
      Wt[(c * 4 + 1) * 68 + r] = wvv.y;
      Wt[(c * 4 + 2) * 68 + r] = wvv.z;
      Wt[(c * 4 + 3) * 68 + r] = wvv.w;
    }
    __syncthreads();
#pragma unroll 4
    for (int kk = 0; kk < 64; kk++) {
      float a[4], b[4];
#pragma unroll
      for (int i = 0; i < 4; i++) a[i] = Xs[(ty * 4 + i) * 68 + kk];
#pragma unroll
      for (int jj = 0; jj < 4; jj++) b[jj] = Wt[kk * 68 + tx * 4 + jj];
#pragma unroll
      for (int i = 0; i < 4; i++)
#pragma unroll
        for (int jj = 0; jj < 4; jj++) acc[i][jj] += a[i] * b[jj];
    }
    __syncthreads();
  }
#pragma unroll
  for (int i = 0; i < 4; i++)
#pragma unroll
    for (int jj = 0; jj < 4; jj++) {
      int n = n0 + tx * 4 + jj;
      Y[(m0 + ty * 4 + i) * 512 + n] = acc[i][jj] + bias[n];
    }
}

// ---------------- batchnorm over batch dim (in-place), optional relu
__global__ __launch_bounds__(256) void bn_kernel(float* __restrict__ Y,
    const float* __restrict__ gam, const float* __restrict__ bet, int relu) {
  const int cx = threadIdx.x & 15;
  const int rg = threadIdx.x >> 4;
  const int col = blockIdx.x * 16 + cx;
  __shared__ float rs[16 * 17], rs2[16 * 17];
  float s = 0.f, s2 = 0.f;
#pragma unroll
  for (int i = 0; i < 8; i++) {
    float v = Y[(rg * 8 + i) * 512 + col];
    s += v; s2 += v * v;
  }
  rs[rg * 17 + cx] = s;
  rs2[rg * 17 + cx] = s2;
  __syncthreads();
  if (threadIdx.x < 16) {
    float S = 0.f, S2 = 0.f;
#pragma unroll
    for (int q = 0; q < 16; q++) { S += rs[q * 17 + threadIdx.x]; S2 += rs2[q * 17 + threadIdx.x]; }
    float mean = S / 128.f;
    float var = S2 / 128.f - mean * mean;
    rs[threadIdx.x] = mean;
    rs2[threadIdx.x] = rsqrtf(var + 1e-5f);
  }
  __syncthreads();
  float mean = rs[cx], rstd = rs2[cx];
  float gv = gam[col], bv = bet[col];
#pragma unroll
  for (int i = 0; i < 8; i++) {
    int idx = (rg * 8 + i) * 512 + col;
    float v = (Y[idx] - mean) * rstd * gv + bv;
    if (relu) v = fmaxf(v, 0.f);
    Y[idx] = v;
  }
}

extern "C" void kernel_launch(void* const* d_in, const int* in_sizes, int n_in,
                              void* d_out, int out_size, void* d_ws, size_t ws_size,
                              hipStream_t stream) {
  const int* label      = (const int*)d_in[0];
  const int* label_len  = (const int*)d_in[1];
  const float* embed_w  = (const float*)d_in[2];
  const float* i2h_w    = (const float*)d_in[3];
  const float* i2h_b    = (const float*)d_in[4];
  const float* h2h_w    = (const float*)d_in[5];
  const float* h2h_b    = (const float*)d_in[6];
  const float* lin0_w   = (const float*)d_in[7];
  const float* lin0_b   = (const float*)d_in[8];
  const float* bn0_g    = (const float*)d_in[9];
  const float* bn0_b    = (const float*)d_in[10];
  const float* lin1_w   = (const float*)d_in[11];
  const float* lin1_b   = (const float*)d_in[12];
  const float* bn1_g    = (const float*)d_in[13];
  const float* bn1_b    = (const float*)d_in[14];
  float* out = (float*)d_out;
  char* ws = (char*)d_ws;

  const size_t OFF_FLAGS = 0;                                      // 16 KB
  const size_t OFF_I2H  = 16384;
  const size_t OFF_PRE  = OFF_I2H + (size_t)2560 * 512 * 2;        // fp16 i2h
  const size_t OFF_H    = OFF_PRE + (size_t)512 * 128 * 2560;      // int8 pre
  const size_t OFF_XSEL = OFF_H + (size_t)2 * 128 * 512 * 2;       // fp16 hfrag
  const size_t OFF_Y0   = OFF_XSEL + (size_t)128 * 512 * 4;

  int* flags = (int*)(ws + OFF_FLAGS);
  _Float16* i2h_h = (_Float16*)(ws + OFF_I2H);
  signed char* pre8 = (signed char*)(ws + OFF_PRE);
  _Float16* hfrag = (_Float16*)(ws + OFF_H);
  float* xsel = (float*)(ws + OFF_XSEL);
  float* y0   = (float*)(ws + OFF_Y0);

  hipMemsetAsync(ws + OFF_FLAGS, 0, 16384, stream);

  {
    int n4 = (2560 * 512) / 4;
    f2h_kernel<<<(n4 + 255) / 256, 256, 0, stream>>>(i2h_w, i2h_h, n4);
  }
  gemm1_kernel<<<dim3(20, 512), 256, 0, stream>>>(label, label_len, embed_w, i2h_h, pre8);
  lstm_kernel<<<dim3(NWG), 256, 0, stream>>>(label_len, h2h_w, h2h_b, i2h_b, pre8, hfrag, xsel, flags);
  fgemm_kernel<<<dim3(8, 2), 256, 0, stream>>>(xsel, lin0_w, lin0_b, y0);
  bn_kernel<<<dim3(32), 256, 0, stream>>>(y0, bn0_g, bn0_b, 1);
  fgemm_kernel<<<dim3(8, 2), 256, 0, stream>>>(y0, lin1_w, lin1_b, out);
  bn_kernel<<<dim3(32), 256, 0, stream>>>(out, bn1_g, bn1_b, 0);
}